// Round 2
// baseline (2062.633 us; speedup 1.0000x reference)
//
#include <hip/hip_runtime.h>

#define NN 50000
#define NE 600000
#define DD 128
#define PSLOTS 1024
#define BN_EPS 1e-5f
#define AGG_EPS 1e-6f

// ---------------- GEMM: C[M,N] = A[M,K] @ W[K,N] + b (optional relu) --------
template <int K, int N, int R, bool RELU>
__global__ void gemm_k(const float* __restrict__ A, const float* __restrict__ W,
                       const float* __restrict__ bias, float* __restrict__ C, int M) {
  __shared__ float As[R][K];
  const int t = threadIdx.x;            // 0..N-1 (output column)
  const int row0 = blockIdx.x * R;
  for (int i = t; i < R * K; i += N) {
    int r = i / K, k = i - r * K;
    int row = row0 + r;
    As[r][k] = (row < M) ? A[(size_t)row * K + k] : 0.f;
  }
  __syncthreads();
  float acc[R];
#pragma unroll
  for (int r = 0; r < R; ++r) acc[r] = 0.f;
  for (int k = 0; k < K; ++k) {
    float w = W[k * N + t];
#pragma unroll
    for (int r = 0; r < R; ++r) acc[r] = fmaf(As[r][k], w, acc[r]);
  }
  const float b = bias[t];
#pragma unroll
  for (int r = 0; r < R; ++r) {
    int row = row0 + r;
    if (row < M) {
      float v = acc[r] + b;
      if (RELU) v = fmaxf(v, 0.f);
      C[(size_t)row * N + t] = v;
    }
  }
}

// ---------------- Edge message + gate + segment sums + e-stats --------------
#define EPB 32
__global__ void edge_kernel(float* __restrict__ eij,         // in: Ce, out: e_ij
                            const int* __restrict__ ei,      // [2, NE]
                            const float* __restrict__ Bx, const float* __restrict__ Dx,
                            const float* __restrict__ Ex,
                            float* __restrict__ num, float* __restrict__ den,
                            float* __restrict__ psum, float* __restrict__ psq) {
  const int c = threadIdx.x;
  const int e0 = blockIdx.x * EPB;
  float s = 0.f, q = 0.f;
  for (int k = 0; k < EPB; ++k) {
    const int eidx = e0 + k;
    const int src = ei[eidx];
    const int dst = ei[NE + eidx];
    const size_t eo = (size_t)eidx * DD + c;
    float v = eij[eo] + Dx[dst * DD + c] + Ex[src * DD + c];
    float sig = 1.f / (1.f + expf(-v));
    eij[eo] = v;
    atomicAdd(&num[dst * DD + c], sig * Bx[src * DD + c]);
    atomicAdd(&den[dst * DD + c], sig);
    s += v;
    q += v * v;
  }
  const int slot = (blockIdx.x & (PSLOTS - 1)) * DD + c;
  atomicAdd(&psum[slot], s);
  atomicAdd(&psq[slot], q);
}

// ---------------- Node-side elementwise kernels -----------------------------
__global__ void node_a(const float* __restrict__ Ax, const float* __restrict__ num,
                       const float* __restrict__ den, float* __restrict__ xb,
                       float* __restrict__ psum, float* __restrict__ psq) {
  const int c = threadIdx.x;
  const int r0 = blockIdx.x * 8;
  float s = 0.f, q = 0.f;
#pragma unroll
  for (int r = 0; r < 8; ++r) {
    int i = (r0 + r) * DD + c;
    float v = Ax[i] + num[i] / (den[i] + AGG_EPS);
    xb[i] = v;
    s += v;
    q += v * v;
  }
  const int slot = (blockIdx.x & (PSLOTS - 1)) * DD + c;
  atomicAdd(&psum[slot], s);
  atomicAdd(&psq[slot], q);
}

__global__ void node_b(const float* __restrict__ x, const float* __restrict__ xb,
                       const float* __restrict__ st, const float* __restrict__ g,
                       const float* __restrict__ be, float* __restrict__ x1,
                       float* __restrict__ psum, float* __restrict__ psq) {
  const int c = threadIdx.x;
  const float m = st[c], rs = st[DD + c], gg = g[c], bb = be[c];
  const int r0 = blockIdx.x * 8;
  float s = 0.f, q = 0.f;
#pragma unroll
  for (int r = 0; r < 8; ++r) {
    int i = (r0 + r) * DD + c;
    float v = x[i] + fmaxf(gg * (xb[i] - m) * rs + bb, 0.f);
    x1[i] = v;
    s += v;
    q += v * v;
  }
  const int slot = (blockIdx.x & (PSLOTS - 1)) * DD + c;
  atomicAdd(&psum[slot], s);
  atomicAdd(&psq[slot], q);
}

__global__ void node_c(const float* __restrict__ x1, const float* __restrict__ st,
                       const float* __restrict__ g, const float* __restrict__ be,
                       float* __restrict__ h) {
  const int c = threadIdx.x;
  const float m = st[c], rs = st[DD + c], gg = g[c], bb = be[c];
  const int r0 = blockIdx.x * 8;
#pragma unroll
  for (int r = 0; r < 8; ++r) {
    int i = (r0 + r) * DD + c;
    h[i] = gg * (x1[i] - m) * rs + bb;
  }
}

__global__ void node_e(const float* __restrict__ h, const float* __restrict__ ub,
                       float* __restrict__ x2,
                       float* __restrict__ psum, float* __restrict__ psq) {
  const int c = threadIdx.x;
  const int r0 = blockIdx.x * 8;
  float s = 0.f, q = 0.f;
#pragma unroll
  for (int r = 0; r < 8; ++r) {
    int i = (r0 + r) * DD + c;
    float v = h[i] + ub[i];
    x2[i] = v;
    s += v;
    q += v * v;
  }
  const int slot = (blockIdx.x & (PSLOTS - 1)) * DD + c;
  atomicAdd(&psum[slot], s);
  atomicAdd(&psq[slot], q);
}

__global__ void node_d(const float* __restrict__ x2, const float* __restrict__ st,
                       const float* __restrict__ g, const float* __restrict__ be,
                       float* __restrict__ out) {
  const int c = threadIdx.x;
  const float m = st[c], rs = st[DD + c], gg = g[c], bb = be[c];
  const int r0 = blockIdx.x * 8;
#pragma unroll
  for (int r = 0; r < 8; ++r) {
    int i = (r0 + r) * DD + c;
    out[i] = gg * (x2[i] - m) * rs + bb;
  }
}

// ---------------- Stats finalize: partials -> (mean, rstd) ------------------
__global__ void finalize_k(const float* __restrict__ psum, const float* __restrict__ psq,
                           float count, float* __restrict__ st) {
  const int c = threadIdx.x;
  float s = 0.f, q = 0.f;
  for (int p = 0; p < PSLOTS; ++p) {
    s += psum[p * DD + c];
    q += psq[p * DD + c];
  }
  float m = s / count;
  float var = q / count - m * m;
  st[c] = m;
  st[DD + c] = rsqrtf(var + BN_EPS);
}

// ---------------- Edge finalize: e_out = e + relu(bn(e_ij)) (in place) ------
__global__ void edge_fin(float* __restrict__ eij, const float* __restrict__ e,
                         const float* __restrict__ st, const float* __restrict__ g,
                         const float* __restrict__ be) {
  const size_t total = (size_t)NE * DD / 4;
  size_t i = (size_t)blockIdx.x * blockDim.x + threadIdx.x;
  if (i >= total) return;
  const int c = (int)((i * 4) & (DD - 1));
  float4 v = reinterpret_cast<float4*>(eij)[i];
  float4 w = reinterpret_cast<const float4*>(e)[i];
  float4 o;
  o.x = w.x + fmaxf(g[c + 0] * (v.x - st[c + 0]) * st[DD + c + 0] + be[c + 0], 0.f);
  o.y = w.y + fmaxf(g[c + 1] * (v.y - st[c + 1]) * st[DD + c + 1] + be[c + 1], 0.f);
  o.z = w.z + fmaxf(g[c + 2] * (v.z - st[c + 2]) * st[DD + c + 2] + be[c + 2], 0.f);
  o.w = w.w + fmaxf(g[c + 3] * (v.w - st[c + 3]) * st[DD + c + 3] + be[c + 3], 0.f);
  reinterpret_cast<float4*>(eij)[i] = o;
}

// ---------------------------------------------------------------------------
extern "C" void kernel_launch(void* const* d_in, const int* in_sizes, int n_in,
                              void* d_out, int out_size, void* d_ws, size_t ws_size,
                              hipStream_t stream) {
  const float* x  = (const float*)d_in[0];
  const float* e  = (const float*)d_in[1];
  const int*   ei = (const int*)d_in[2];
  const float* WA = (const float*)d_in[3];  const float* bA = (const float*)d_in[4];
  const float* WB = (const float*)d_in[5];  const float* bB = (const float*)d_in[6];
  const float* WC = (const float*)d_in[7];  const float* bC = (const float*)d_in[8];
  const float* WD = (const float*)d_in[9];  const float* bD = (const float*)d_in[10];
  const float* WE = (const float*)d_in[11]; const float* bE = (const float*)d_in[12];
  const float* g_x = (const float*)d_in[13]; const float* be_x = (const float*)d_in[14];
  const float* g_e = (const float*)d_in[15]; const float* be_e = (const float*)d_in[16];
  const float* Wf1 = (const float*)d_in[17]; const float* bf1 = (const float*)d_in[18];
  const float* Wf2 = (const float*)d_in[19]; const float* bf2 = (const float*)d_in[20];
  const float* g_n1 = (const float*)d_in[21]; const float* be_n1 = (const float*)d_in[22];
  const float* g_n2 = (const float*)d_in[23]; const float* be_n2 = (const float*)d_in[24];

  float* out_x = (float*)d_out;
  float* out_e = out_x + (size_t)NN * DD;

  const size_t ND = (size_t)NN * DD;
  float* ws  = (float*)d_ws;
  float* Ax  = ws;
  float* Bx  = ws + ND;
  float* Dx  = ws + 2 * ND;
  float* Ex  = ws + 3 * ND;
  float* num = ws + 4 * ND;
  float* den = ws + 5 * ND;
  float* part  = ws + 6 * ND;                       // 8 * PSLOTS * DD
  float* stats = part + 8 * (size_t)PSLOTS * DD;    // 4 * 256
  // buffer reuse (lifetimes verified):
  float* xb = Bx;   // after edge_kernel consumed Bx
  float* x1 = Dx;   // after edge_kernel consumed Dx
  float* h  = Ex;   // after edge_kernel consumed Ex
  float* tb = ws;   // [0, 2*ND): Ax dead after node_a, xb dead after node_b
  float* ub = den;  // den dead after node_a
  float* x2 = num;  // num dead after node_a

  float* pE  = part;
  float* pX  = part + 2 * (size_t)PSLOTS * DD;
  float* pN1 = part + 4 * (size_t)PSLOTS * DD;
  float* pN2 = part + 6 * (size_t)PSLOTS * DD;
  float* sE  = stats;
  float* sX  = stats + 256;
  float* sN1 = stats + 512;
  float* sN2 = stats + 768;

  // zero num, den, all stat partials + stats
  size_t zbytes = (2 * ND + 8 * (size_t)PSLOTS * DD + 1024) * sizeof(float);
  hipMemsetAsync(num, 0, zbytes, stream);

  // Linear layers
  gemm_k<128, 128, 8, false><<<NN / 8, 128, 0, stream>>>(x, WA, bA, Ax, NN);
  gemm_k<128, 128, 8, false><<<NN / 8, 128, 0, stream>>>(x, WB, bB, Bx, NN);
  gemm_k<128, 128, 8, false><<<NN / 8, 128, 0, stream>>>(x, WD, bD, Dx, NN);
  gemm_k<128, 128, 8, false><<<NN / 8, 128, 0, stream>>>(x, WE, bE, Ex, NN);
  gemm_k<128, 128, 8, false><<<NE / 8, 128, 0, stream>>>(e, WC, bC, out_e, NE);  // Ce

  // Edge message, gate, aggregation, e-stats
  edge_kernel<<<NE / EPB, 128, 0, stream>>>(out_e, ei, Bx, Dx, Ex, num, den,
                                            pE, pE + (size_t)PSLOTS * DD);
  // x_out pre-BN + x-stats
  node_a<<<NN / 8, 128, 0, stream>>>(Ax, num, den, xb, pX, pX + (size_t)PSLOTS * DD);

  finalize_k<<<1, 128, 0, stream>>>(pE, pE + (size_t)PSLOTS * DD, (float)NE, sE);
  finalize_k<<<1, 128, 0, stream>>>(pX, pX + (size_t)PSLOTS * DD, (float)NN, sX);

  // x1 = x + relu(bn_x(xb)); n1 stats
  node_b<<<NN / 8, 128, 0, stream>>>(x, xb, sX, g_x, be_x, x1,
                                     pN1, pN1 + (size_t)PSLOTS * DD);
  finalize_k<<<1, 128, 0, stream>>>(pN1, pN1 + (size_t)PSLOTS * DD, (float)NN, sN1);

  // h = bn_n1(x1)
  node_c<<<NN / 8, 128, 0, stream>>>(x1, sN1, g_n1, be_n1, h);

  // FFN
  gemm_k<128, 256, 8, true><<<NN / 8, 256, 0, stream>>>(h, Wf1, bf1, tb, NN);
  gemm_k<256, 128, 8, false><<<NN / 8, 128, 0, stream>>>(tb, Wf2, bf2, ub, NN);

  // x2 = h + ffn; n2 stats
  node_e<<<NN / 8, 128, 0, stream>>>(h, ub, x2, pN2, pN2 + (size_t)PSLOTS * DD);
  finalize_k<<<1, 128, 0, stream>>>(pN2, pN2 + (size_t)PSLOTS * DD, (float)NN, sN2);

  // final x output
  node_d<<<NN / 8, 128, 0, stream>>>(x2, sN2, g_n2, be_n2, out_x);

  // e_out = e + relu(bn_e(e_ij)), in place in d_out
  edge_fin<<<(NE * DD / 4 + 255) / 256, 256, 0, stream>>>(out_e, e, sE, g_e, be_e);
}